// Round 7
// baseline (123.216 us; speedup 1.0000x reference)
//
#include <hip/hip_runtime.h>

#define NN   4096
#define MM   8191   // 2*NN - 1
#define BB   256
#define CAP  256    // u16 slots per row (nnz/row ~41, max ~70)

__device__ __forceinline__ int prefix_lt(unsigned long long m) {
    return __builtin_amdgcn_mbcnt_hi((unsigned)(m >> 32),
           __builtin_amdgcn_mbcnt_lo((unsigned)m, 0u));
}

// round-to-nearest-even pack of two f32 into 2x bf16 in one uint
__device__ __forceinline__ unsigned pack2bf(float lo, float hi) {
    unsigned a = __float_as_uint(lo);
    unsigned b = __float_as_uint(hi);
    a += 0x7fffu + ((a >> 16) & 1u);
    b += 0x7fffu + ((b >> 16) & 1u);
    return (a >> 16) | (b & 0xffff0000u);
}

// ---------------------------------------------------------------------------
// k_prep: zero w1sum[256]; pack dd = bf16(d1 - d2) (2 MB). One float4/thread.
// ---------------------------------------------------------------------------
__global__ __launch_bounds__(256) void k_prep(const float4* __restrict__ d1,
                                              const float4* __restrict__ d2,
                                              float* __restrict__ w1sum,
                                              uint2* __restrict__ ddp,
                                              int make_dd) {
    int idx = blockIdx.x * 256 + threadIdx.x;
    if (idx < BB) w1sum[idx] = 0.0f;
    if (make_dd) {
        float4 a = d1[idx], b = d2[idx];
        uint2 r;
        r.x = pack2bf(a.x - b.x, a.y - b.y);
        r.y = pack2bf(a.z - b.z, a.w - b.w);
        ddp[idx] = r;
    }
}

// ---------------------------------------------------------------------------
// k_compact: one wave per ROW. Two sequential 8-load halves per row;
// ballot+mbcnt compaction into per-wave u16 LDS buffer; direct cnt[m] store;
// uint4 writeout. reps is a runtime arg (1 for production).
// ---------------------------------------------------------------------------
__global__ __launch_bounds__(256, 4) void k_compact(
        const float4* __restrict__ st4,
        int* __restrict__ cnt,
        unsigned short* __restrict__ list,
        int reps) {
    __shared__ unsigned short s_buf[4][CAP];
    const int wave = threadIdx.x >> 6;
    const int lane = threadIdx.x & 63;
    unsigned short* buf = s_buf[wave];
    const int m = blockIdx.x * 4 + wave;

    for (int rep = 0; rep < reps; ++rep) {
        if (m >= MM) continue;
        int c = 0;
        #pragma unroll
        for (int h = 0; h < 2; ++h) {
            const float4* base = st4 + (size_t)m * (NN / 4) + h * (NN / 8);
            float4 v0 = base[lane];
            float4 v1 = base[64  + lane];
            float4 v2 = base[128 + lane];
            float4 v3 = base[192 + lane];
            float4 v4 = base[256 + lane];
            float4 v5 = base[320 + lane];
            float4 v6 = base[384 + lane];
            float4 v7 = base[448 + lane];

            const int cb = h * (NN / 2);
            #define SITE(val, col)                                          \
            {                                                               \
                unsigned long long mk = __ballot((val) != 0.0f);            \
                if ((val) != 0.0f)                                          \
                    buf[c + prefix_lt(mk)] = (unsigned short)(col);         \
                c += __popcll(mk);                                          \
            }
            #define QUAD(v, cb0)                                            \
                SITE(v.x, (cb0))     SITE(v.y, (cb0) + 1)                   \
                SITE(v.z, (cb0) + 2) SITE(v.w, (cb0) + 3)
            QUAD(v0, cb + (lane)       * 4)
            QUAD(v1, cb + (64  + lane) * 4)
            QUAD(v2, cb + (128 + lane) * 4)
            QUAD(v3, cb + (192 + lane) * 4)
            QUAD(v4, cb + (256 + lane) * 4)
            QUAD(v5, cb + (320 + lane) * 4)
            QUAD(v6, cb + (384 + lane) * 4)
            QUAD(v7, cb + (448 + lane) * 4)
            #undef QUAD
            #undef SITE
        }
        __builtin_amdgcn_wave_barrier();   // LDS writes before reads

        if (lane == 0) cnt[m] = c;
        uint4* lv = (uint4*)(list + (size_t)m * CAP);
        const int nv = (c + 7) >> 3;
        if (lane < nv) lv[lane] = ((const uint4*)buf)[lane];
        __builtin_amdgcn_wave_barrier();   // reads before next rep's writes
    }
}

// ---------------------------------------------------------------------------
// k_gather: one wave per row. List preloaded to LDS (8B/lane, one load);
// 4-deep uint2 (4x bf16 cols/lane) gathers from the 2 MB packed dd.
// reps is a runtime arg: only rep 0's sums are kept (exactness), later reps
// re-execute the loads (runtime trip count -> no unroll/DCE).
// ---------------------------------------------------------------------------
__global__ __launch_bounds__(256, 8) void k_gather(
        const uint2* __restrict__ ddp,
        const int* __restrict__ cnt,
        const unsigned short* __restrict__ list,
        const float* __restrict__ param,
        const int*   __restrict__ parents,
        float* __restrict__ w1sum,
        int reps) {
    __shared__ unsigned long long s_listq[4][CAP / 4];   // 64 qwords/wave
    __shared__ float s_part[BB];
    const int tid  = threadIdx.x;
    const int wave = tid >> 6;
    const int lane = tid & 63;

    s_part[tid] = 0.0f;
    __syncthreads();

    const int m = blockIdx.x * 4 + wave;
    float r0 = 0.f, r1 = 0.f, r2 = 0.f, r3 = 0.f;
    float wgt = 0.0f;

    if (m < MM) {
        int c = cnt[m];
        if (c > CAP) c = CAP;
        const unsigned long long* lsrc =
            (const unsigned long long*)(list + (size_t)m * CAP);
        s_listq[wave][lane] = lsrc[lane];
        __builtin_amdgcn_wave_barrier();
        wgt = param[parents[m]] - param[m];

        #define UNP0(u) __uint_as_float((u) << 16)
        #define UNP1(u) __uint_as_float((u) & 0xffff0000u)
        for (int rep = 0; rep < reps; ++rep) {
            float c0 = 0.f, c1 = 0.f, c2 = 0.f, c3 = 0.f;
            float e0 = 0.f, e1 = 0.f, e2 = 0.f, e3 = 0.f;
            int i = 0;
            for (; i + 4 <= c; i += 4) {
                unsigned long long pk = s_listq[wave][i >> 2];
                int n0 = (int)( pk        & 0xffffULL);
                int n1 = (int)((pk >> 16) & 0xffffULL);
                int n2 = (int)((pk >> 32) & 0xffffULL);
                int n3 = (int)((pk >> 48) & 0xffffULL);
                uint2 g0 = ddp[(size_t)n0 * 64 + lane];
                uint2 g1 = ddp[(size_t)n1 * 64 + lane];
                uint2 g2 = ddp[(size_t)n2 * 64 + lane];
                uint2 g3 = ddp[(size_t)n3 * 64 + lane];
                c0 += UNP0(g0.x); c1 += UNP1(g0.x); c2 += UNP0(g0.y); c3 += UNP1(g0.y);
                e0 += UNP0(g1.x); e1 += UNP1(g1.x); e2 += UNP0(g1.y); e3 += UNP1(g1.y);
                c0 += UNP0(g2.x); c1 += UNP1(g2.x); c2 += UNP0(g2.y); c3 += UNP1(g2.y);
                e0 += UNP0(g3.x); e1 += UNP1(g3.x); e2 += UNP0(g3.y); e3 += UNP1(g3.y);
            }
            for (; i < c; ++i) {
                int n = (int)((s_listq[wave][i >> 2] >> ((i & 3) * 16)) & 0xffffULL);
                uint2 g = ddp[(size_t)n * 64 + lane];
                c0 += UNP0(g.x); c1 += UNP1(g.x); c2 += UNP0(g.y); c3 += UNP1(g.y);
            }
            if (rep == 0) {
                r0 = c0 + e0; r1 = c1 + e1; r2 = c2 + e2; r3 = c3 + e3;
            }
        }
        #undef UNP0
        #undef UNP1
    }

    atomicAdd(&s_part[4 * lane + 0], wgt * fabsf(r0));
    atomicAdd(&s_part[4 * lane + 1], wgt * fabsf(r1));
    atomicAdd(&s_part[4 * lane + 2], wgt * fabsf(r2));
    atomicAdd(&s_part[4 * lane + 3], wgt * fabsf(r3));
    __syncthreads();
    atomicAdd(&w1sum[tid], s_part[tid]);
}

// ---------------------------------------------------------------------------
// k_finalize: out = sum_b (ot[b] - 0.5 * w1sum[b])^2
// ---------------------------------------------------------------------------
__global__ __launch_bounds__(256) void k_finalize(const float* __restrict__ w1sum,
                                                  const float* __restrict__ ot,
                                                  float* __restrict__ out) {
    __shared__ float s[4];
    int tid = threadIdx.x;
    float e = ot[tid] - 0.5f * w1sum[tid];
    float v = e * e;
    #pragma unroll
    for (int off = 32; off > 0; off >>= 1) v += __shfl_down(v, off, 64);
    if ((tid & 63) == 0) s[tid >> 6] = v;
    __syncthreads();
    if (tid == 0) out[0] = (s[0] + s[1]) + (s[2] + s[3]);
}

// ---------------------------------------------------------------------------
extern "C" void kernel_launch(void* const* d_in, const int* in_sizes, int n_in,
                              void* d_out, int out_size, void* d_ws, size_t ws_size,
                              hipStream_t stream) {
    const float* d1      = (const float*)d_in[0];
    const float* d2      = (const float*)d_in[1];
    const float* ot      = (const float*)d_in[2];
    const float* subtree = (const float*)d_in[3];
    const float* param   = (const float*)d_in[4];
    const int*   parents = (const int*)d_in[5];

    char* wsb = (char*)d_ws;
    float* w1sum = (float*)wsb;                       // 256 f
    int*   cnt   = (int*)(wsb + 1024);                // MM ints
    size_t off = 1024 + (size_t)MM * 4;
    off = (off + 15) & ~(size_t)15;                   // 33792

    const size_t listbytes = (size_t)MM * CAP * 2;    // ~4.2 MB
    unsigned short* list = (unsigned short*)(wsb + off);
    size_t ddoff = (off + listbytes + 15) & ~(size_t)15;
    uint2* ddp = (uint2*)(wsb + ddoff);               // 2 MB packed bf16

    k_prep<<<1024, 256, 0, stream>>>((const float4*)d1, (const float4*)d2,
                                     w1sum, ddp, 1);
    k_compact<<<2048, 256, 0, stream>>>((const float4*)subtree, cnt, list, 1);
    k_gather<<<2048, 256, 0, stream>>>(ddp, cnt, list, param, parents, w1sum, 5);
    k_finalize<<<1, 256, 0, stream>>>(w1sum, ot, (float*)d_out);
}

// Round 8
// 91.611 us; speedup vs baseline: 1.3450x; 1.3450x over previous
//
#include <hip/hip_runtime.h>

#define NN   4096
#define MM   8191   // 2*NN - 1
#define BB   256
#define CAP  256    // u16 slots per row (nnz/row ~41, max ~70)

__device__ __forceinline__ int prefix_lt(unsigned long long m) {
    return __builtin_amdgcn_mbcnt_hi((unsigned)(m >> 32),
           __builtin_amdgcn_mbcnt_lo((unsigned)m, 0u));
}

// round-to-nearest-even pack of two f32 into 2x bf16 in one uint
__device__ __forceinline__ unsigned pack2bf(float lo, float hi) {
    unsigned a = __float_as_uint(lo);
    unsigned b = __float_as_uint(hi);
    a += 0x7fffu + ((a >> 16) & 1u);
    b += 0x7fffu + ((b >> 16) & 1u);
    return (a >> 16) | (b & 0xffff0000u);
}

// ---------------------------------------------------------------------------
// k_prep: zero w1sum[256]; pack dd = bf16(d1 - d2) (2 MB). One float4/thread.
// ---------------------------------------------------------------------------
__global__ __launch_bounds__(256) void k_prep(const float4* __restrict__ d1,
                                              const float4* __restrict__ d2,
                                              float* __restrict__ w1sum,
                                              uint2* __restrict__ ddp) {
    int idx = blockIdx.x * 256 + threadIdx.x;
    if (idx < BB) w1sum[idx] = 0.0f;
    float4 a = d1[idx], b = d2[idx];
    uint2 r;
    r.x = pack2bf(a.x - b.x, a.y - b.y);
    r.y = pack2bf(a.z - b.z, a.w - b.w);
    ddp[idx] = r;
}

// ---------------------------------------------------------------------------
// k_compact: one wave per ROW (at the 6.2 TB/s stream roofline per R7).
// Two sequential 8-load halves per row; ballot+mbcnt compaction into
// per-wave u16 LDS buffer; direct cnt[m] store; uint4 writeout.
// ---------------------------------------------------------------------------
__global__ __launch_bounds__(256, 4) void k_compact(
        const float4* __restrict__ st4,
        int* __restrict__ cnt,
        unsigned short* __restrict__ list) {
    __shared__ unsigned short s_buf[4][CAP];
    const int wave = threadIdx.x >> 6;
    const int lane = threadIdx.x & 63;
    unsigned short* buf = s_buf[wave];
    const int m = blockIdx.x * 4 + wave;
    if (m >= MM) return;

    int c = 0;
    #pragma unroll
    for (int h = 0; h < 2; ++h) {
        const float4* base = st4 + (size_t)m * (NN / 4) + h * (NN / 8);
        float4 v0 = base[lane];
        float4 v1 = base[64  + lane];
        float4 v2 = base[128 + lane];
        float4 v3 = base[192 + lane];
        float4 v4 = base[256 + lane];
        float4 v5 = base[320 + lane];
        float4 v6 = base[384 + lane];
        float4 v7 = base[448 + lane];

        const int cb = h * (NN / 2);
        #define SITE(val, col)                                          \
        {                                                               \
            unsigned long long mk = __ballot((val) != 0.0f);            \
            if ((val) != 0.0f)                                          \
                buf[c + prefix_lt(mk)] = (unsigned short)(col);         \
            c += __popcll(mk);                                          \
        }
        #define QUAD(v, cb0)                                            \
            SITE(v.x, (cb0))     SITE(v.y, (cb0) + 1)                   \
            SITE(v.z, (cb0) + 2) SITE(v.w, (cb0) + 3)
        QUAD(v0, cb + (lane)       * 4)
        QUAD(v1, cb + (64  + lane) * 4)
        QUAD(v2, cb + (128 + lane) * 4)
        QUAD(v3, cb + (192 + lane) * 4)
        QUAD(v4, cb + (256 + lane) * 4)
        QUAD(v5, cb + (320 + lane) * 4)
        QUAD(v6, cb + (384 + lane) * 4)
        QUAD(v7, cb + (448 + lane) * 4)
        #undef QUAD
        #undef SITE
    }
    __builtin_amdgcn_wave_barrier();   // LDS writes before reads

    if (lane == 0) cnt[m] = c;
    uint4* lv = (uint4*)(list + (size_t)m * CAP);
    const int nv = (c + 7) >> 3;
    if (lane < nv) lv[lane] = ((const uint4*)buf)[lane];
}

// ---------------------------------------------------------------------------
// k_gather: one wave per row. List preloaded to LDS (8B/lane, one load);
// 8-deep uint2 (4x bf16 cols/lane) gathers from the 2 MB L2-resident packed
// dd -> 8 independent loads in flight per round (R7: 4-deep was ILP-bound,
// VGPR_Count=20).
// ---------------------------------------------------------------------------
__global__ __launch_bounds__(256, 8) void k_gather(
        const uint2* __restrict__ ddp,
        const int* __restrict__ cnt,
        const unsigned short* __restrict__ list,
        const float* __restrict__ param,
        const int*   __restrict__ parents,
        float* __restrict__ w1sum) {
    __shared__ unsigned long long s_listq[4][CAP / 4];   // 64 qwords/wave
    __shared__ float s_part[BB];
    const int tid  = threadIdx.x;
    const int wave = tid >> 6;
    const int lane = tid & 63;

    s_part[tid] = 0.0f;
    __syncthreads();

    const int m = blockIdx.x * 4 + wave;
    float c0 = 0.f, c1 = 0.f, c2 = 0.f, c3 = 0.f;
    float e0 = 0.f, e1 = 0.f, e2 = 0.f, e3 = 0.f;
    float wgt = 0.0f;

    if (m < MM) {
        int c = cnt[m];
        if (c > CAP) c = CAP;
        const unsigned long long* lsrc =
            (const unsigned long long*)(list + (size_t)m * CAP);
        s_listq[wave][lane] = lsrc[lane];
        __builtin_amdgcn_wave_barrier();
        wgt = param[parents[m]] - param[m];

        #define UNP0(u) __uint_as_float((u) << 16)
        #define UNP1(u) __uint_as_float((u) & 0xffff0000u)
        #define ACCA(g) { c0 += UNP0(g.x); c1 += UNP1(g.x); c2 += UNP0(g.y); c3 += UNP1(g.y); }
        #define ACCB(g) { e0 += UNP0(g.x); e1 += UNP1(g.x); e2 += UNP0(g.y); e3 += UNP1(g.y); }
        int i = 0;
        for (; i + 8 <= c; i += 8) {
            unsigned long long pk0 = s_listq[wave][i >> 2];
            unsigned long long pk1 = s_listq[wave][(i >> 2) + 1];
            int n0 = (int)( pk0        & 0xffffULL);
            int n1 = (int)((pk0 >> 16) & 0xffffULL);
            int n2 = (int)((pk0 >> 32) & 0xffffULL);
            int n3 = (int)((pk0 >> 48) & 0xffffULL);
            int n4 = (int)( pk1        & 0xffffULL);
            int n5 = (int)((pk1 >> 16) & 0xffffULL);
            int n6 = (int)((pk1 >> 32) & 0xffffULL);
            int n7 = (int)((pk1 >> 48) & 0xffffULL);
            uint2 g0 = ddp[(size_t)n0 * 64 + lane];
            uint2 g1 = ddp[(size_t)n1 * 64 + lane];
            uint2 g2 = ddp[(size_t)n2 * 64 + lane];
            uint2 g3 = ddp[(size_t)n3 * 64 + lane];
            uint2 g4 = ddp[(size_t)n4 * 64 + lane];
            uint2 g5 = ddp[(size_t)n5 * 64 + lane];
            uint2 g6 = ddp[(size_t)n6 * 64 + lane];
            uint2 g7 = ddp[(size_t)n7 * 64 + lane];
            ACCA(g0) ACCB(g1) ACCA(g2) ACCB(g3)
            ACCA(g4) ACCB(g5) ACCA(g6) ACCB(g7)
        }
        for (; i + 4 <= c; i += 4) {
            unsigned long long pk = s_listq[wave][i >> 2];
            int n0 = (int)( pk        & 0xffffULL);
            int n1 = (int)((pk >> 16) & 0xffffULL);
            int n2 = (int)((pk >> 32) & 0xffffULL);
            int n3 = (int)((pk >> 48) & 0xffffULL);
            uint2 g0 = ddp[(size_t)n0 * 64 + lane];
            uint2 g1 = ddp[(size_t)n1 * 64 + lane];
            uint2 g2 = ddp[(size_t)n2 * 64 + lane];
            uint2 g3 = ddp[(size_t)n3 * 64 + lane];
            ACCA(g0) ACCB(g1) ACCA(g2) ACCB(g3)
        }
        for (; i < c; ++i) {
            int n = (int)((s_listq[wave][i >> 2] >> ((i & 3) * 16)) & 0xffffULL);
            uint2 g = ddp[(size_t)n * 64 + lane];
            ACCA(g)
        }
        #undef ACCA
        #undef ACCB
        #undef UNP0
        #undef UNP1
    }

    atomicAdd(&s_part[4 * lane + 0], wgt * fabsf(c0 + e0));
    atomicAdd(&s_part[4 * lane + 1], wgt * fabsf(c1 + e1));
    atomicAdd(&s_part[4 * lane + 2], wgt * fabsf(c2 + e2));
    atomicAdd(&s_part[4 * lane + 3], wgt * fabsf(c3 + e3));
    __syncthreads();
    atomicAdd(&w1sum[tid], s_part[tid]);
}

// ---------------------------------------------------------------------------
// k_finalize: out = sum_b (ot[b] - 0.5 * w1sum[b])^2
// ---------------------------------------------------------------------------
__global__ __launch_bounds__(256) void k_finalize(const float* __restrict__ w1sum,
                                                  const float* __restrict__ ot,
                                                  float* __restrict__ out) {
    __shared__ float s[4];
    int tid = threadIdx.x;
    float e = ot[tid] - 0.5f * w1sum[tid];
    float v = e * e;
    #pragma unroll
    for (int off = 32; off > 0; off >>= 1) v += __shfl_down(v, off, 64);
    if ((tid & 63) == 0) s[tid >> 6] = v;
    __syncthreads();
    if (tid == 0) out[0] = (s[0] + s[1]) + (s[2] + s[3]);
}

// ---------------------------------------------------------------------------
extern "C" void kernel_launch(void* const* d_in, const int* in_sizes, int n_in,
                              void* d_out, int out_size, void* d_ws, size_t ws_size,
                              hipStream_t stream) {
    const float* d1      = (const float*)d_in[0];
    const float* d2      = (const float*)d_in[1];
    const float* ot      = (const float*)d_in[2];
    const float* subtree = (const float*)d_in[3];
    const float* param   = (const float*)d_in[4];
    const int*   parents = (const int*)d_in[5];

    char* wsb = (char*)d_ws;
    float* w1sum = (float*)wsb;                       // 256 f
    int*   cnt   = (int*)(wsb + 1024);                // MM ints
    size_t off = 1024 + (size_t)MM * 4;
    off = (off + 15) & ~(size_t)15;                   // 33792

    const size_t listbytes = (size_t)MM * CAP * 2;    // ~4.2 MB
    unsigned short* list = (unsigned short*)(wsb + off);
    size_t ddoff = (off + listbytes + 15) & ~(size_t)15;
    uint2* ddp = (uint2*)(wsb + ddoff);               // 2 MB packed bf16

    k_prep<<<1024, 256, 0, stream>>>((const float4*)d1, (const float4*)d2,
                                     w1sum, ddp);
    k_compact<<<2048, 256, 0, stream>>>((const float4*)subtree, cnt, list);
    k_gather<<<2048, 256, 0, stream>>>(ddp, cnt, list, param, parents, w1sum);
    k_finalize<<<1, 256, 0, stream>>>(w1sum, ot, (float*)d_out);
}